// Round 8
// baseline (314.665 us; speedup 1.0000x reference)
//
#include <hip/hip_runtime.h>
#include <math.h>

#define NIN 91392        // 17*21*16*16
#define DIN 8
#define DOUT 16
#define BATCH 16
#define NSLICE 1632      // blocks; each owns 7 contiguous chunks: 1632*7*8 = 91392 n
#define KCH 7            // chunks (of 8 n) per block
#define TPB 256

// Pass kernel: recompute u_hat[j,n,o] = sum_i x[b,n,i]*W[j,n,i,o] on the fly.
// Thread t = (g:3)(j:1)(o:4); block = slice of 56 contiguous n.
// x for all 7 chunks staged in LDS up front (28 KB); W 2-deep prefetch pipeline.
// amdgpu_waves_per_eu(4,4): pin 4 waves/EU <-> 128-VGPR budget, no spills.
// PASS 0: s0 partial = sum_n u (c=0.5 folded into reduce)
// PASS>0: d via 32-lane butterfly, c = sigmoid(sgn*d), s partial
template<int PASS>
__global__ __launch_bounds__(TPB)
__attribute__((amdgpu_waves_per_eu(4, 4)))
void caps_pass(
    const float* __restrict__ x, const float* __restrict__ W,
    const float* __restrict__ vin, float* __restrict__ part)
{
    const int t = threadIdx.x;
    const int o = t & 15;          // output dim
    const int j = (t >> 4) & 1;    // capsule
    const int g = t >> 5;          // n-subgroup 0..7
    const int slice = blockIdx.x;

    // xs layout: [k][b][g*8+i] flat floats; 7*16*64 = 7168 floats = 28 KB
    __shared__ __align__(16) float xs[KCH * BATCH * 64];

    // stage x: 1792 float4s, 7 per thread; 256B coalesced runs per (k,b)
    #pragma unroll
    for (int r = 0; r < KCH; ++r) {
        const int q = r * 256 + t;        // float4 index
        const int k = q >> 8;             // chunk 0..6
        const int b = (q >> 4) & 15;      // batch
        const int pos = q & 15;           // float4 within 64-float run
        *(float4*)(xs + (size_t)q * 4) =
            *(const float4*)(x + (size_t)b * (NIN * DIN)
                               + ((size_t)slice * KCH + k) * 64 + pos * 4);
    }

    const float sgn = j ? -1.f : 1.f;

    float vinreg[BATCH];
    if (PASS > 0) {
        #pragma unroll
        for (int b = 0; b < BATCH; ++b)
            vinreg[b] = sgn * vin[b * 32 + (t & 31)];
    }

    float acc[BATCH];
    #pragma unroll
    for (int b = 0; b < BATCH; ++b) acc[b] = 0.f;

    // W[j][n][i][o], n = slice*56 + k*8 + g; chunk stride = 1024 floats
    const float* wp = W + ((size_t)j * NIN + (size_t)slice * (KCH * 8) + g) * (DIN * DOUT) + o;
    float w[3][DIN];                 // rotating 2-deep prefetch buffers
    #pragma unroll
    for (int i = 0; i < DIN; ++i) w[0][i] = wp[i * DOUT];
    #pragma unroll
    for (int i = 0; i < DIN; ++i) w[1][i] = wp[1024 + i * DOUT];

    __syncthreads();   // xs ready

    #pragma unroll
    for (int k = 0; k < KCH; ++k) {
        // prefetch chunk k+2 while computing chunk k (covers ~900cy HBM latency)
        if (k + 2 < KCH) {
            const float* wpf = wp + (size_t)(k + 2) * 1024;
            #pragma unroll
            for (int i = 0; i < DIN; ++i) w[(k + 2) % 3][i] = wpf[i * DOUT];
        }

        const float* xk = xs + k * (BATCH * 64) + g * 8;
        const float* wc = w[k % 3];    // compile-time index (k fully unrolled)
        #pragma unroll
        for (int b = 0; b < BATCH; ++b) {
            const float4 xa = *(const float4*)(xk + b * 64);
            const float4 xb = *(const float4*)(xk + b * 64 + 4);
            float u = xa.x*wc[0] + xa.y*wc[1] + xa.z*wc[2] + xa.w*wc[3]
                    + xb.x*wc[4] + xb.y*wc[5] + xb.z*wc[6] + xb.w*wc[7];
            if (PASS == 0) {
                acc[b] += u;
            } else {
                float m = vinreg[b] * u;           // sgn folded in
                m += __shfl_xor(m, 1);
                m += __shfl_xor(m, 2);
                m += __shfl_xor(m, 4);
                m += __shfl_xor(m, 8);
                m += __shfl_xor(m, 16);            // 32-lane (j,o) reduce -> d
                const float cc = __builtin_amdgcn_rcpf(1.f + __expf(-sgn * m));
                acc[b] += cc * u;
            }
        }
    }

    // fold the two 32-lane halves of each wave
    #pragma unroll
    for (int b = 0; b < BATCH; ++b) acc[b] += __shfl_xor(acc[b], 32);

    // cross-wave reduce, reusing xs (stride 17 -> conflict-free)
    __syncthreads();
    float* red = xs;   // [(wave*32+lane)*17 + b], 128*17 = 2176 floats
    const int wave = t >> 6;
    const int lane = t & 63;
    if (lane < 32) {
        #pragma unroll
        for (int b = 0; b < BATCH; ++b) red[(wave * 32 + lane) * 17 + b] = acc[b];
    }
    __syncthreads();
    if (t < 32) {
        #pragma unroll
        for (int b = 0; b < BATCH; ++b) {
            float s = red[(0 * 32 + t) * 17 + b] + red[(1 * 32 + t) * 17 + b]
                    + red[(2 * 32 + t) * 17 + b] + red[(3 * 32 + t) * 17 + b];
            // column-major partials: part[col][slice], col = b*32 + (j*16+o)
            part[((size_t)b * 32 + t) * NSLICE + slice] = s;
        }
    }
}

// Reduce partials -> s[b,j,o], squash -> v. 32 blocks = one per (b,j).
// PASS 0: scale 0.5 (uniform softmax), write v0
// PASS 1: write v0+v1 (logits linear in accumulated v)
// PASS 2: write final v
template<int PASS>
__global__ __launch_bounds__(256) void caps_reduce(
    const float* __restrict__ part, const float* __restrict__ vprev,
    float* __restrict__ vout)
{
    const int blk = blockIdx.x;   // b*2 + j
    const int b = blk >> 1, j = blk & 1;
    const int t = threadIdx.x;
    const int o = t & 15;
    const int ch = t >> 4;
    const size_t base = ((size_t)b * 32 + j * 16 + o) * NSLICE;
    float s = 0.f;
    for (int g = ch; g < NSLICE; g += 16) s += part[base + g];
    __shared__ float red[256];
    red[t] = s;
    __syncthreads();
    if (t < 16) {
        float sv = 0.f;
        #pragma unroll
        for (int c = 0; c < 16; ++c) sv += red[c * 16 + t];
        if (PASS == 0) sv *= 0.5f;
        float sq = sv * sv;
        sq += __shfl_xor(sq, 1);
        sq += __shfl_xor(sq, 2);
        sq += __shfl_xor(sq, 4);
        sq += __shfl_xor(sq, 8);
        const float sn = sq;
        float v = sv * sn / ((1.f + sn) * sqrtf(sn + 1e-7f));
        if (PASS == 1) v += vprev[b * 32 + j * 16 + o];
        vout[b * 32 + j * 16 + o] = v;
    }
}

extern "C" void kernel_launch(void* const* d_in, const int* in_sizes, int n_in,
                              void* d_out, int out_size, void* d_ws, size_t ws_size,
                              hipStream_t stream) {
    const float* x = (const float*)d_in[0];
    const float* W = (const float*)d_in[1];
    float* out = (float*)d_out;

    float* part = (float*)d_ws;                       // 512*1632 floats = 3.34MB
    float* v0   = part + (size_t)512 * NSLICE;        // 512
    float* vsum = v0 + 512;                           // 512

    caps_pass<0><<<NSLICE, TPB, 0, stream>>>(x, W, nullptr, part);
    caps_reduce<0><<<32, 256, 0, stream>>>(part, nullptr, v0);
    caps_pass<1><<<NSLICE, TPB, 0, stream>>>(x, W, v0, part);
    caps_reduce<1><<<32, 256, 0, stream>>>(part, v0, vsum);
    caps_pass<2><<<NSLICE, TPB, 0, stream>>>(x, W, vsum, part);
    caps_reduce<2><<<32, 256, 0, stream>>>(part, nullptr, out);
}

// Round 9
// 218.835 us; speedup vs baseline: 1.4379x; 1.4379x over previous
//
#include <hip/hip_runtime.h>
#include <math.h>

#define NIN 91392        // 17*21*16*16
#define DIN 8
#define DOUT 16
#define BATCH 16
#define KCH 8            // chunks (of 8 n) per block: 64 contiguous n
#define NSLICE 1428      // blocks: 1428 * 64 = 91392 n
#define TPB 512          // 8 waves; wave w owns batches {2w, 2w+1}

// Pass kernel: recompute u_hat[j,n,o] = sum_i x[b,n,i]*W[j,n,i,o] on the fly.
// lane = (g:3)(j:1)(og:2): g = n-in-chunk, j = capsule, og = o-group of 4.
// Wave w handles batches 2w,2w+1 -> acc/vin are 2 float4 each: fits <64 VGPR
// (R7/R8 lesson: allocator hard-caps at 64; must fit by construction).
// W read as float4 (16B/lane, o-contiguous); x float4 broadcast within 8-lane
// (j,og) groups. No LDS, no __syncthreads: all reductions are 6 shuffles.
// PASS 0: s0 partial = sum_n u (c=0.5 folded into reduce)
// PASS>0: d = v.u diff over (j,o) via 3-shuffle butterfly, c = sigmoid(sgn*d)
template<int PASS>
__global__ __launch_bounds__(TPB) void caps_pass(
    const float* __restrict__ x, const float* __restrict__ W,
    const float* __restrict__ vin, float* __restrict__ part)
{
    const int t = threadIdx.x;
    const int lane = t & 63;
    const int wave = t >> 6;          // 0..7
    const int og = lane & 3;          // o-group: o = og*4..og*4+3
    const int j  = (lane >> 2) & 1;   // capsule
    const int g  = lane >> 3;         // n within chunk, 0..7
    const int slice = blockIdx.x;
    const int b0 = wave * 2;

    const float sgn = j ? -1.f : 1.f;

    float4 vin4[2];
    if (PASS > 0) {
        #pragma unroll
        for (int b = 0; b < 2; ++b) {
            float4 v = *(const float4*)(vin + (b0 + b) * 32 + j * 16 + og * 4);
            vin4[b] = make_float4(sgn * v.x, sgn * v.y, sgn * v.z, sgn * v.w);
        }
    }

    float4 acc0 = make_float4(0.f, 0.f, 0.f, 0.f);
    float4 acc1 = make_float4(0.f, 0.f, 0.f, 0.f);

    #pragma unroll
    for (int k = 0; k < KCH; ++k) {
        const int n = slice * (KCH * 8) + k * 8 + g;
        const float* wp  = W + ((size_t)j * NIN + n) * (DIN * DOUT) + og * 4;
        const float* xp0 = x + ((size_t)(b0 + 0) * NIN + n) * DIN;
        const float* xp1 = x + ((size_t)(b0 + 1) * NIN + n) * DIN;

        // x[b][n][0..7] into scalar regs (constant indices -> SROA to VGPRs)
        float x0[DIN], x1[DIN];
        {
            const float4 a = *(const float4*)(xp0);
            const float4 c = *(const float4*)(xp0 + 4);
            x0[0]=a.x; x0[1]=a.y; x0[2]=a.z; x0[3]=a.w;
            x0[4]=c.x; x0[5]=c.y; x0[6]=c.z; x0[7]=c.w;
            const float4 a1 = *(const float4*)(xp1);
            const float4 c1 = *(const float4*)(xp1 + 4);
            x1[0]=a1.x; x1[1]=a1.y; x1[2]=a1.z; x1[3]=a1.w;
            x1[4]=c1.x; x1[5]=c1.y; x1[6]=c1.z; x1[7]=c1.w;
        }

        float4 u0 = make_float4(0.f, 0.f, 0.f, 0.f);
        float4 u1 = make_float4(0.f, 0.f, 0.f, 0.f);
        #pragma unroll
        for (int i = 0; i < DIN; ++i) {
            const float4 w4 = *(const float4*)(wp + i * DOUT);  // 64B-step imm offsets
            u0.x += x0[i] * w4.x;  u0.y += x0[i] * w4.y;
            u0.z += x0[i] * w4.z;  u0.w += x0[i] * w4.w;
            u1.x += x1[i] * w4.x;  u1.y += x1[i] * w4.y;
            u1.z += x1[i] * w4.z;  u1.w += x1[i] * w4.w;
        }

        if (PASS == 0) {
            acc0.x += u0.x; acc0.y += u0.y; acc0.z += u0.z; acc0.w += u0.w;
            acc1.x += u1.x; acc1.y += u1.y; acc1.z += u1.z; acc1.w += u1.w;
        } else {
            // d = b_0 - b_1: per-lane partial sgn*(v.u over own 4 o), then
            // butterfly over (og,j) lanes = bits 0..2
            float m0 = vin4[0].x*u0.x + vin4[0].y*u0.y + vin4[0].z*u0.z + vin4[0].w*u0.w;
            float m1 = vin4[1].x*u1.x + vin4[1].y*u1.y + vin4[1].z*u1.z + vin4[1].w*u1.w;
            m0 += __shfl_xor(m0, 1);  m1 += __shfl_xor(m1, 1);
            m0 += __shfl_xor(m0, 2);  m1 += __shfl_xor(m1, 2);
            m0 += __shfl_xor(m0, 4);  m1 += __shfl_xor(m1, 4);
            const float c0 = __builtin_amdgcn_rcpf(1.f + __expf(-sgn * m0));
            const float c1 = __builtin_amdgcn_rcpf(1.f + __expf(-sgn * m1));
            acc0.x += c0 * u0.x; acc0.y += c0 * u0.y;
            acc0.z += c0 * u0.z; acc0.w += c0 * u0.w;
            acc1.x += c1 * u1.x; acc1.y += c1 * u1.y;
            acc1.z += c1 * u1.z; acc1.w += c1 * u1.w;
        }
    }

    // g-reduction (bits 3..5), pure shuffles, no LDS
    #pragma unroll
    for (int s = 8; s <= 32; s <<= 1) {
        acc0.x += __shfl_xor(acc0.x, s); acc0.y += __shfl_xor(acc0.y, s);
        acc0.z += __shfl_xor(acc0.z, s); acc0.w += __shfl_xor(acc0.w, s);
        acc1.x += __shfl_xor(acc1.x, s); acc1.y += __shfl_xor(acc1.y, s);
        acc1.z += __shfl_xor(acc1.z, s); acc1.w += __shfl_xor(acc1.w, s);
    }
    if (g == 0) {
        // column-major partials: part[col][slice], col = b*32 + j*16 + o
        const size_t c0 = ((size_t)(b0 + 0) * 32 + j * 16 + og * 4) * NSLICE + slice;
        const size_t c1 = ((size_t)(b0 + 1) * 32 + j * 16 + og * 4) * NSLICE + slice;
        part[c0 + 0 * NSLICE] = acc0.x;  part[c0 + 1 * NSLICE] = acc0.y;
        part[c0 + 2 * NSLICE] = acc0.z;  part[c0 + 3 * NSLICE] = acc0.w;
        part[c1 + 0 * NSLICE] = acc1.x;  part[c1 + 1 * NSLICE] = acc1.y;
        part[c1 + 2 * NSLICE] = acc1.z;  part[c1 + 3 * NSLICE] = acc1.w;
    }
}

// Reduce partials -> s[b,j,o], squash -> v. 32 blocks = one per (b,j).
// PASS 0: scale 0.5 (uniform softmax), write v0
// PASS 1: write v0+v1 (logits linear in accumulated v)
// PASS 2: write final v
template<int PASS>
__global__ __launch_bounds__(256) void caps_reduce(
    const float* __restrict__ part, const float* __restrict__ vprev,
    float* __restrict__ vout)
{
    const int blk = blockIdx.x;   // b*2 + j
    const int b = blk >> 1, j = blk & 1;
    const int t = threadIdx.x;
    const int o = t & 15;
    const int ch = t >> 4;
    const size_t base = ((size_t)b * 32 + j * 16 + o) * NSLICE;
    float s = 0.f;
    for (int g = ch; g < NSLICE; g += 16) s += part[base + g];
    __shared__ float red[256];
    red[t] = s;
    __syncthreads();
    if (t < 16) {
        float sv = 0.f;
        #pragma unroll
        for (int c = 0; c < 16; ++c) sv += red[c * 16 + t];
        if (PASS == 0) sv *= 0.5f;
        float sq = sv * sv;
        sq += __shfl_xor(sq, 1);
        sq += __shfl_xor(sq, 2);
        sq += __shfl_xor(sq, 4);
        sq += __shfl_xor(sq, 8);
        const float sn = sq;
        float v = sv * sn / ((1.f + sn) * sqrtf(sn + 1e-7f));
        if (PASS == 1) v += vprev[b * 32 + j * 16 + o];
        vout[b * 32 + j * 16 + o] = v;
    }
}

extern "C" void kernel_launch(void* const* d_in, const int* in_sizes, int n_in,
                              void* d_out, int out_size, void* d_ws, size_t ws_size,
                              hipStream_t stream) {
    const float* x = (const float*)d_in[0];
    const float* W = (const float*)d_in[1];
    float* out = (float*)d_out;

    float* part = (float*)d_ws;                       // 512*1428 floats = 2.9MB
    float* v0   = part + (size_t)512 * NSLICE;        // 512
    float* vsum = v0 + 512;                           // 512

    caps_pass<0><<<NSLICE, TPB, 0, stream>>>(x, W, nullptr, part);
    caps_reduce<0><<<32, 256, 0, stream>>>(part, nullptr, v0);
    caps_pass<1><<<NSLICE, TPB, 0, stream>>>(x, W, v0, part);
    caps_reduce<1><<<32, 256, 0, stream>>>(part, v0, vsum);
    caps_pass<2><<<NSLICE, TPB, 0, stream>>>(x, W, vsum, part);
    caps_reduce<2><<<32, 256, 0, stream>>>(part, nullptr, out);
}